// Round 1
// baseline (732.500 us; speedup 1.0000x reference)
//
#include <hip/hip_runtime.h>

constexpr int IND = 128;
constexpr int HD  = 96;
constexpr int OD  = 64;
constexpr int NL  = 4;

struct F3 { float x, y, z; };

__global__ __launch_bounds__(256) void k_hist(const int* __restrict__ dst, int* __restrict__ deg, int E) {
    int e = blockIdx.x * 256 + threadIdx.x;
    if (e < E) atomicAdd(&deg[dst[e]], 1);
}

__global__ __launch_bounds__(256) void k_scan1(const int* __restrict__ deg, int* __restrict__ bsum, int n) {
    int tid = threadIdx.x;
    int base = blockIdx.x * 1024 + tid * 4;
    int s = 0;
    #pragma unroll
    for (int q = 0; q < 4; ++q) { int i = base + q; if (i < n) s += deg[i]; }
    #pragma unroll
    for (int o = 32; o > 0; o >>= 1) s += __shfl_xor(s, o);
    __shared__ int wsum[4];
    int lane = tid & 63, wid = tid >> 6;
    if (lane == 0) wsum[wid] = s;
    __syncthreads();
    if (tid == 0) bsum[blockIdx.x] = wsum[0] + wsum[1] + wsum[2] + wsum[3];
}

// single wave: scan block sums (nb <= 64), also write row_ptr[n] = E
__global__ void k_scan2(const int* __restrict__ bsum, int* __restrict__ boff, int nb,
                        int* __restrict__ row_ptr, int n, int E) {
    int l = threadIdx.x;
    int v = (l < nb) ? bsum[l] : 0;
    int incl = v;
    #pragma unroll
    for (int o = 1; o < 64; o <<= 1) { int t = __shfl_up(incl, o); if (l >= o) incl += t; }
    if (l < nb) boff[l] = incl - v;
    if (l == 0) row_ptr[n] = E;
}

__global__ __launch_bounds__(256) void k_scan3(const int* __restrict__ deg, const int* __restrict__ boff,
                                               int* __restrict__ row_ptr, int n) {
    int tid = threadIdx.x;
    int base = blockIdx.x * 1024 + tid * 4;
    int d[4];
    #pragma unroll
    for (int q = 0; q < 4; ++q) { int i = base + q; d[q] = (i < n) ? deg[i] : 0; }
    int tsum = d[0] + d[1] + d[2] + d[3];
    int incl = tsum;
    #pragma unroll
    for (int o = 1; o < 64; o <<= 1) { int t = __shfl_up(incl, o); if ((tid & 63) >= o) incl += t; }
    __shared__ int wsum[4];
    int lane = tid & 63, wid = tid >> 6;
    if (lane == 63) wsum[wid] = incl;
    __syncthreads();
    int woff = 0;
    for (int w = 0; w < wid; ++w) woff += wsum[w];
    int run = boff[blockIdx.x] + woff + (incl - tsum);
    #pragma unroll
    for (int q = 0; q < 4; ++q) {
        int i = base + q;
        if (i < n) { row_ptr[i] = run; run += d[q]; }
    }
}

__global__ __launch_bounds__(256) void k_fill(const int* __restrict__ src, const int* __restrict__ dst,
                                              const int* __restrict__ row_ptr, int* __restrict__ cursor,
                                              int* __restrict__ srcp, int* __restrict__ eidp, int E) {
    int e = blockIdx.x * 256 + threadIdx.x;
    if (e >= E) return;
    int d = dst[e];
    int pos = atomicAdd(&cursor[d], 1);
    int slot = row_ptr[d] + pos;
    srcp[slot] = src[e];
    eidp[slot] = e;
}

// A0[v,:] = sum_{e->v} ew0[e]*h[src[e],:] ;  A1 likewise.  32 lanes per node, 3 floats/lane.
__global__ __launch_bounds__(256) void k_agg(const float* __restrict__ h, const int* __restrict__ row_ptr,
                                             const int* __restrict__ srcp, const int* __restrict__ eidp,
                                             const float* __restrict__ ew0, const float* __restrict__ ew1,
                                             float* __restrict__ A0, float* __restrict__ A1, int n) {
    int g = blockIdx.x * 8 + (threadIdx.x >> 5);
    int lane = threadIdx.x & 31;
    if (g >= n) return;
    int beg = row_ptr[g], end = row_ptr[g + 1];
    float a0x = 0.f, a0y = 0.f, a0z = 0.f;
    float a1x = 0.f, a1y = 0.f, a1z = 0.f;
    int off = lane * 3;
    for (int i = beg; i < end; ++i) {
        int s = srcp[i];
        int e = eidp[i];
        float w0 = ew0[e];
        float w1 = ew1[e];
        F3 v = *(const F3*)(h + (size_t)s * HD + off);
        a0x = fmaf(w0, v.x, a0x); a0y = fmaf(w0, v.y, a0y); a0z = fmaf(w0, v.z, a0z);
        a1x = fmaf(w1, v.x, a1x); a1y = fmaf(w1, v.y, a1y); a1z = fmaf(w1, v.z, a1z);
    }
    float* p0 = A0 + (size_t)g * HD + off;
    p0[0] = a0x; p0[1] = a0y; p0[2] = a0z;
    float* p1 = A1 + (size_t)g * HD + off;
    p1[0] = a1x; p1[1] = a1y; p1[2] = a1z;
}

// out = [relu]( A0@W0 [+ A1@W1] [+ bias] )   A: nrows x K row-major, W: K x NO row-major.
// Block: 512 threads, tile 128 rows x NO cols. Thread: 8 rows (8*ty..) x NC cols (tx+32j).
template<int K, int NO, bool DUAL, bool RELU, bool BIAS>
__global__ __launch_bounds__(512) void k_gemm(const float* __restrict__ A0p, const float* __restrict__ A1p,
                                              const float* __restrict__ W0p, const float* __restrict__ W1p,
                                              const float* __restrict__ bias,
                                              float* __restrict__ out, int nrows) {
    constexpr int BR = 128, KB = 32;
    constexpr int NC = NO / 32;
    __shared__ float sA[KB][BR];   // transposed: [k][row]
    __shared__ float sW[KB][NO];
    int tid = threadIdx.x;
    int tx = tid & 31;
    int ty = tid >> 5;             // 0..15
    int brow = blockIdx.x * BR;

    float acc[8][NC];
    #pragma unroll
    for (int r = 0; r < 8; ++r)
        #pragma unroll
        for (int j = 0; j < NC; ++j) acc[r][j] = 0.f;

    int srow = tid >> 2;           // 0..127  (staging row)
    int squart = tid & 3;

    #pragma unroll
    for (int head = 0; head < (DUAL ? 2 : 1); ++head) {
        const float* A = (head == 0) ? A0p : A1p;
        const float* W = (head == 0) ? W0p : W1p;
        for (int kc = 0; kc < K; kc += KB) {
            __syncthreads();
            // stage A chunk (transpose to [k][row])
            {
                int gr = brow + srow;
                const float* ap = A + (size_t)gr * K + kc;
                #pragma unroll
                for (int i = 0; i < 2; ++i) {
                    int f4 = squart + 4 * i;          // 0..7
                    float4 v = make_float4(0.f, 0.f, 0.f, 0.f);
                    if (gr < nrows) v = *(const float4*)(ap + 4 * f4);
                    int kk = 4 * f4;
                    sA[kk + 0][srow] = v.x;
                    sA[kk + 1][srow] = v.y;
                    sA[kk + 2][srow] = v.z;
                    sA[kk + 3][srow] = v.w;
                }
            }
            // stage W chunk (contiguous copy)
            {
                const float4* wp4 = (const float4*)(W + kc * NO);
                float4* sw4 = (float4*)&sW[0][0];
                constexpr int TOT4 = KB * NO / 4;
                for (int i = tid; i < TOT4; i += 512) sw4[i] = wp4[i];
            }
            __syncthreads();
            #pragma unroll
            for (int kk = 0; kk < KB; ++kk) {
                float a[8];
                #pragma unroll
                for (int q = 0; q < 2; ++q) {
                    float4 v = *(const float4*)&sA[kk][8 * ty + 4 * q];
                    a[4 * q + 0] = v.x; a[4 * q + 1] = v.y;
                    a[4 * q + 2] = v.z; a[4 * q + 3] = v.w;
                }
                float wv[NC];
                #pragma unroll
                for (int j = 0; j < NC; ++j) wv[j] = sW[kk][tx + 32 * j];
                #pragma unroll
                for (int r = 0; r < 8; ++r)
                    #pragma unroll
                    for (int j = 0; j < NC; ++j)
                        acc[r][j] = fmaf(a[r], wv[j], acc[r][j]);
            }
        }
    }
    #pragma unroll
    for (int r = 0; r < 8; ++r) {
        int gr = brow + 8 * ty + r;
        if (gr < nrows) {
            #pragma unroll
            for (int j = 0; j < NC; ++j) {
                int c = tx + 32 * j;
                float v = acc[r][j];
                if (BIAS) v += bias[c];
                if (RELU) v = fmaxf(v, 0.f);
                out[(size_t)gr * NO + c] = v;
            }
        }
    }
}

extern "C" void kernel_launch(void* const* d_in, const int* in_sizes, int n_in,
                              void* d_out, int out_size, void* d_ws, size_t ws_size,
                              hipStream_t stream) {
    const float* x     = (const float*)d_in[0];
    const int*   ei    = (const int*)  d_in[1];
    const float* enc_w = (const float*)d_in[2];
    const float* enc_b = (const float*)d_in[3];
    const float* dec_w = (const float*)d_in[4];
    const float* dec_b = (const float*)d_in[5];
    const float* convW = (const float*)d_in[6];
    const float* convE = (const float*)d_in[7];

    const int N = in_sizes[0] / IND;
    const int E = in_sizes[1] / 2;
    const int* src = ei;
    const int* dst = ei + E;
    float* fout = (float*)d_out;

    char* wp = (char*)d_ws;
    auto carve = [&](size_t bytes) -> void* {
        void* p = (void*)wp;
        wp += (bytes + 255) & ~(size_t)255;
        return p;
    };
    int* deg     = (int*)carve(2 * (size_t)N * 4);   // deg | cursor adjacent (one memset)
    int* cursor  = deg + N;
    int* row_ptr = (int*)carve(((size_t)N + 1) * 4);
    int* bsum    = (int*)carve(64 * 4);
    int* boff    = (int*)carve(64 * 4);
    int* srcp    = (int*)carve((size_t)E * 4);
    int* eidp    = (int*)carve((size_t)E * 4);
    float* hbuf  = (float*)carve((size_t)N * HD * 4);
    float* Ag0   = (float*)carve((size_t)N * HD * 4);
    float* Ag1   = (float*)carve((size_t)N * HD * 4);

    hipMemsetAsync(deg, 0, 2 * (size_t)N * 4, stream);

    int ebl = (E + 255) / 256;
    int nb  = (N + 1023) / 1024;
    k_hist<<<ebl, 256, 0, stream>>>(dst, deg, E);
    k_scan1<<<nb, 256, 0, stream>>>(deg, bsum, N);
    k_scan2<<<1, 64, 0, stream>>>(bsum, boff, nb, row_ptr, N, E);
    k_scan3<<<nb, 256, 0, stream>>>(deg, boff, row_ptr, N);
    k_fill<<<ebl, 256, 0, stream>>>(src, dst, row_ptr, cursor, srcp, eidp, E);

    int gbl = (N + 127) / 128;
    // encoder: h = relu(x @ enc_w + enc_b)
    k_gemm<IND, HD, false, true, true><<<gbl, 512, 0, stream>>>(x, nullptr, enc_w, nullptr, enc_b, hbuf, N);

    float* hfin = fout + (size_t)N * OD;   // output-1 region doubles as final-h storage
    for (int l = 0; l < NL; ++l) {
        const float* W0 = convW + ((size_t)l * 2 + 0) * HD * HD;
        const float* W1 = convW + ((size_t)l * 2 + 1) * HD * HD;
        const float* e0 = convE + ((size_t)l * 2 + 0) * E;
        const float* e1 = convE + ((size_t)l * 2 + 1) * E;
        k_agg<<<(N + 7) / 8, 256, 0, stream>>>(hbuf, row_ptr, srcp, eidp, e0, e1, Ag0, Ag1, N);
        float* ho = (l == NL - 1) ? hfin : hbuf;
        k_gemm<HD, HD, true, true, false><<<gbl, 512, 0, stream>>>(Ag0, Ag1, W0, W1, nullptr, ho, N);
    }
    // decoder: out0 = hfin @ dec_w + dec_b
    k_gemm<HD, OD, false, false, true><<<gbl, 512, 0, stream>>>(hfin, nullptr, dec_w, nullptr, dec_b, fout, N);
}